// Round 3
// baseline (2016.883 us; speedup 1.0000x reference)
//
#include <hip/hip_runtime.h>
#include <math.h>

// Problem constants (B, CIN, CGD, CE, G, H, W) = (4, 256, 256, 64, 4, 80, 80)
#define NB    4
#define CINC  256
#define NCE   64
#define NG    4
#define NPIX  6400          // H*W
#define NROWS 132           // 64 embed + 64 guide_embed + 4 conf
#define CHG   65            // tree-filter channels per group (64 + norm)
#define CHP   80            // padded per-group stride in agg (80*4B = 320B, 64B-aligned)
#define NODEF (NG*CHP)      // 320 floats per node, 1280B = 20 cache lines (line-aligned)
#define TEPS  1e-8f
#define TP    128           // gemm position tile
#define KC    32            // gemm K chunk

// ---------------------------------------------------------------------------
// Preprocessing: per batch — levels via pointer doubling, level starts,
// child ranges (parent[] is monotone => contiguous children), inverse order.
// ---------------------------------------------------------------------------
__global__ __launch_bounds__(256) void prep_kernel(
    const int* __restrict__ order, const int* __restrict__ parent,
    int* __restrict__ cs, int* __restrict__ ce, int* __restrict__ ls,
    int* __restrict__ nl, int* __restrict__ inv)
{
  const int b = blockIdx.x;
  const int tid = threadIdx.x;
  const int* par = parent + b*NPIX;
  const int* ord = order + b*NPIX;
  __shared__ int lvl[NPIX];   // 25.6 KB
  __shared__ int anc[NPIX];   // 25.6 KB
  __shared__ int smax;

  #pragma unroll
  for (int it = 0; it < NPIX/256; ++it) {
    int k = tid + it*256;
    int p = par[k];
    lvl[k] = (k == 0) ? 0 : 1;
    anc[k] = p;
    inv[b*NPIX + ord[k]] = k;
    cs[b*NPIX + k] = 0;
    ce[b*NPIX + k] = 0;
  }
  __syncthreads();

  // depth via pointer doubling: 13 rounds (2^13 = 8192 > 6400)
  for (int r = 0; r < 13; ++r) {
    int nlv[NPIX/256], nan_[NPIX/256];
    #pragma unroll
    for (int it = 0; it < NPIX/256; ++it) {
      int k = tid + it*256;
      int a = anc[k];
      nlv[it]  = lvl[k] + lvl[a];
      nan_[it] = anc[a];
    }
    __syncthreads();
    #pragma unroll
    for (int it = 0; it < NPIX/256; ++it) {
      int k = tid + it*256;
      lvl[k] = nlv[it];
      anc[k] = nan_[it];
    }
    __syncthreads();
  }

  if (tid == 0) smax = 0;
  __syncthreads();
  int m = 0;
  #pragma unroll
  for (int it = 0; it < NPIX/256; ++it) m = max(m, lvl[tid + it*256]);
  atomicMax(&smax, m);
  __syncthreads();
  if (tid == 0) {
    nl[b] = smax + 1;
    ls[b*(NPIX+2) + smax + 1] = NPIX;
  }
  #pragma unroll
  for (int it = 0; it < NPIX/256; ++it) {
    int k = tid + it*256;
    // levels are contiguous position ranges (BFS order)
    if (k == 0 || lvl[k] != lvl[k-1]) ls[b*(NPIX+2) + lvl[k]] = k;
    if (k >= 1) {
      int p = par[k];
      if (k == 1      || par[k-1] != p) cs[b*NPIX + p] = k;
      if (k == NPIX-1 || par[k+1] != p) ce[b*NPIX + p] = k + 1;
    }
  }
}

// ---------------------------------------------------------------------------
// GEMM: emb_all[b][n][r], r in [0,64)=W_embed@f, [64,128)=W_guide@g,
// [128,132)=sigmoid(W_conf@f). Node-major output for later gathers.
// ---------------------------------------------------------------------------
__global__ __launch_bounds__(512) void gemm_kernel(
    const float* __restrict__ f, const float* __restrict__ g,
    const float* __restrict__ We, const float* __restrict__ Wc,
    const float* __restrict__ Wg, float* __restrict__ emb)
{
  const int b  = blockIdx.y;
  const int t0 = blockIdx.x * TP;
  const int tid = threadIdx.x;
  const int i = tid >> 5;   // 0..15 (row group)
  const int j = tid & 31;   // 0..31 (position)

  __shared__ float fT[KC][TP];     // 16 KB
  __shared__ float gT[KC][TP];     // 16 KB
  __shared__ float wT[NROWS][KC];  // 16.9 KB

  float acc[9][4];
  #pragma unroll
  for (int a = 0; a < 9; ++a)
    #pragma unroll
    for (int p = 0; p < 4; ++p) acc[a][p] = 0.f;

  const float* fb = f + (size_t)b*CINC*NPIX;
  const float* gb = g + (size_t)b*CINC*NPIX;

  for (int kc = 0; kc < CINC; kc += KC) {
    // stage f/g tiles: KC*TP = 4096 floats, 8 per thread (two float4 loads)
    {
      int idx = tid * 8;
      int kk = idx / TP, p = idx - kk*TP;
      const float4* srcf = reinterpret_cast<const float4*>(fb + (size_t)(kc+kk)*NPIX + t0 + p);
      const float4* srcg = reinterpret_cast<const float4*>(gb + (size_t)(kc+kk)*NPIX + t0 + p);
      float4 v0 = srcf[0], v1 = srcf[1];
      fT[kk][p+0]=v0.x; fT[kk][p+1]=v0.y; fT[kk][p+2]=v0.z; fT[kk][p+3]=v0.w;
      fT[kk][p+4]=v1.x; fT[kk][p+5]=v1.y; fT[kk][p+6]=v1.z; fT[kk][p+7]=v1.w;
      v0 = srcg[0]; v1 = srcg[1];
      gT[kk][p+0]=v0.x; gT[kk][p+1]=v0.y; gT[kk][p+2]=v0.z; gT[kk][p+3]=v0.w;
      gT[kk][p+4]=v1.x; gT[kk][p+5]=v1.y; gT[kk][p+6]=v1.z; gT[kk][p+7]=v1.w;
    }
    // stage W chunk: 132*32 = 4224 floats = 528 x 8  (528 > blockDim -> loop!)
    for (int s = tid; s < 528; s += 512) {
      int idx = s * 8;
      int r = idx / KC, kb = idx - r*KC;
      const float* wsrc;
      if (r < 64)       wsrc = We + r*CINC + kc + kb;
      else if (r < 128) wsrc = Wg + (r-64)*CINC + kc + kb;
      else              wsrc = Wc + (r-128)*CINC + kc + kb;
      const float4* wv = reinterpret_cast<const float4*>(wsrc);
      float4 v0 = wv[0], v1 = wv[1];
      wT[r][kb+0]=v0.x; wT[r][kb+1]=v0.y; wT[r][kb+2]=v0.z; wT[r][kb+3]=v0.w;
      wT[r][kb+4]=v1.x; wT[r][kb+5]=v1.y; wT[r][kb+6]=v1.z; wT[r][kb+7]=v1.w;
    }
    __syncthreads();

    #pragma unroll 4
    for (int kk = 0; kk < KC; ++kk) {
      float xf0 = fT[kk][j], xf1 = fT[kk][j+32], xf2 = fT[kk][j+64], xf3 = fT[kk][j+96];
      float xg0 = gT[kk][j], xg1 = gT[kk][j+32], xg2 = gT[kk][j+64], xg3 = gT[kk][j+96];
      #pragma unroll
      for (int rr = 0; rr < 4; ++rr) {       // rows 0..63: from f
        float a = wT[i + 16*rr][kk];
        acc[rr][0] += a*xf0; acc[rr][1] += a*xf1; acc[rr][2] += a*xf2; acc[rr][3] += a*xf3;
      }
      #pragma unroll
      for (int rr = 4; rr < 8; ++rr) {       // rows 64..127: from g
        float a = wT[i + 16*rr][kk];
        acc[rr][0] += a*xg0; acc[rr][1] += a*xg1; acc[rr][2] += a*xg2; acc[rr][3] += a*xg3;
      }
      if (i < 4) {                           // rows 128..131: conf, from f
        float a = wT[128 + i][kk];
        acc[8][0] += a*xf0; acc[8][1] += a*xf1; acc[8][2] += a*xf2; acc[8][3] += a*xf3;
      }
    }
    __syncthreads();
  }

  float* eb = emb + (size_t)b*NPIX*NROWS;
  #pragma unroll
  for (int rr = 0; rr < 8; ++rr) {
    int r = i + 16*rr;
    #pragma unroll
    for (int p = 0; p < 4; ++p) {
      int n = t0 + j + 32*p;
      eb[(size_t)n*NROWS + r] = acc[rr][p];
    }
  }
  if (i < 4) {
    int r = 128 + i;
    #pragma unroll
    for (int p = 0; p < 4; ++p) {
      int n = t0 + j + 32*p;
      eb[(size_t)n*NROWS + r] = 1.f / (1.f + expf(-acc[8][p]));
    }
  }
}

// ---------------------------------------------------------------------------
// Edge weights in ordered space: w[b][k][g] = exp(-(d_e+d_g+beta^2))
// ---------------------------------------------------------------------------
__global__ __launch_bounds__(256) void wdist_kernel(
    const float* __restrict__ emb, const int* __restrict__ order,
    const int* __restrict__ parent, const float* __restrict__ beta,
    float* __restrict__ w)
{
  int idx = blockIdx.x*256 + threadIdx.x;   // b*NPIX + k
  int b = idx / NPIX;
  int n  = order[idx];
  int kp = parent[idx];
  int np = order[b*NPIX + kp];
  const float4* e0 = reinterpret_cast<const float4*>(emb + ((size_t)b*NPIX + n )*NROWS);
  const float4* e1 = reinterpret_cast<const float4*>(emb + ((size_t)b*NPIX + np)*NROWS);
  float d[NG] = {0.f, 0.f, 0.f, 0.f};
  #pragma unroll
  for (int q = 0; q < 32; ++q) {            // channels 0..127 (embed then guide_embed)
    float4 a = e0[q], c = e1[q];
    int gg = (q & 15) >> 2;                 // group = (channel%64)/16
    float t0 = a.x-c.x, t1 = a.y-c.y, t2 = a.z-c.z, t3 = a.w-c.w;
    d[gg] += t0*t0 + t1*t1 + t2*t2 + t3*t3;
  }
  #pragma unroll
  for (int gg = 0; gg < NG; ++gg) {
    float bg = beta[gg];
    w[(size_t)idx*NG + gg] = expf(-(d[gg] + bg*bg));
  }
}

// ---------------------------------------------------------------------------
// x in spatial space: xsp[b][n][g*65+c] = f[g*64+c]*conf[g]; c=64 -> conf[g]
// ---------------------------------------------------------------------------
__global__ __launch_bounds__(256) void xbuild_kernel(
    const float* __restrict__ f, const float* __restrict__ emb,
    float* __restrict__ xsp)
{
  int idx = blockIdx.x*256 + threadIdx.x;   // b*NPIX + n
  int b = idx / NPIX, n = idx - b*NPIX;
  const float* eb = emb + (size_t)idx*NROWS;
  float cf[NG];
  #pragma unroll
  for (int gg = 0; gg < NG; ++gg) cf[gg] = eb[128 + gg];
  const float* fb = f + (size_t)b*CINC*NPIX + n;
  float* xb = xsp + (size_t)idx*260;
  #pragma unroll 4
  for (int ch = 0; ch < CINC; ++ch) {
    int gg = ch >> 6, cc = ch & 63;
    xb[gg*CHG + cc] = fb[(size_t)ch*NPIX] * cf[gg];
  }
  #pragma unroll
  for (int gg = 0; gg < NG; ++gg) xb[gg*CHG + 64] = cf[gg];
}

// ---------------------------------------------------------------------------
// Gather x to BFS-ordered, padded agg layout: agg[b][k][g*80+c]
// ---------------------------------------------------------------------------
__global__ __launch_bounds__(256) void gather_kernel(
    const float* __restrict__ xsp, const int* __restrict__ order,
    float* __restrict__ agg)
{
  int blk = blockIdx.x;                     // b*100 + chunk
  int b = blk / 100, k0 = (blk - b*100) * 64;
  for (int t = threadIdx.x; t < 64*260; t += 256) {
    int node = t / 260, jj = t - node*260;
    int k = k0 + node;
    int n = order[b*NPIX + k];
    int gg = jj / CHG, cc = jj - gg*CHG;
    agg[((size_t)b*NPIX + k)*NODEF + gg*CHP + cc] = xsp[((size_t)b*NPIX + n)*260 + jj];
  }
}

// ---------------------------------------------------------------------------
// Tree filter: level-synchronous up (child gather, no atomics) + down
// (in-place). One block per (batch, group); only __syncthreads needed.
// ---------------------------------------------------------------------------
__global__ __launch_bounds__(256) void sweep_kernel(
    float* __restrict__ agg, const float* __restrict__ w,
    const int* __restrict__ parent, const int* __restrict__ cs,
    const int* __restrict__ ce, const int* __restrict__ ls,
    const int* __restrict__ nl)
{
  const int b  = blockIdx.x >> 2;
  const int gg = blockIdx.x & 3;
  const int* lsb = ls + b*(NPIX+2);
  const int L = nl[b];
  float* ab = agg + (size_t)b*NPIX*NODEF + gg*CHP;
  const float* wb = w + (size_t)b*NPIX*NG + gg;
  const int* csb = cs + b*NPIX;
  const int* ceb = ce + b*NPIX;
  const int* pb  = parent + b*NPIX;

  // UP: agg[p] += sum_children w[k]*agg[k], deepest level first
  for (int lev = L-2; lev >= 0; --lev) {
    const int s = lsb[lev], e = lsb[lev+1];
    const int items = (e - s) * CHG;
    for (int t = threadIdx.x; t < items; t += 256) {
      int node = t / CHG, c = t - node*CHG;
      int p = s + node;
      float* ap = ab + (size_t)p*NODEF;
      float v = ap[c];
      const int j1 = ceb[p];
      for (int j = csb[p]; j < j1; ++j)
        v += wb[(size_t)j*NG] * ab[(size_t)j*NODEF + c];
      ap[c] = v;
    }
    __syncthreads();
  }
  // DOWN (in place): out[k] = agg[k] + w[k]*(out[parent] - w[k]*agg[k])
  for (int lev = 1; lev < L; ++lev) {
    const int s = lsb[lev], e = lsb[lev+1];
    const int items = (e - s) * CHG;
    for (int t = threadIdx.x; t < items; t += 256) {
      int node = t / CHG, c = t - node*CHG;
      int k = s + node;
      float wk = wb[(size_t)k*NG];
      int p = pb[k];
      float a  = ab[(size_t)k*NODEF + c];
      float op = ab[(size_t)p*NODEF + c];
      ab[(size_t)k*NODEF + c] = a + wk*(op - wk*a);
    }
    __syncthreads();
  }
}

// ---------------------------------------------------------------------------
// Epilogue: scatter back to spatial, normalize, residual, store
// ---------------------------------------------------------------------------
__global__ __launch_bounds__(256) void epilogue_kernel(
    const float* __restrict__ agg, const int* __restrict__ inv,
    const float* __restrict__ f, const float* __restrict__ gamma,
    float* __restrict__ out)
{
  int idx = blockIdx.x*256 + threadIdx.x;   // b*NPIX + n
  int b = idx / NPIX, n = idx - b*NPIX;
  int k = inv[idx];
  const float* ab = agg + ((size_t)b*NPIX + k)*NODEF;
  float gam = gamma[0];
  const float* fb = f + (size_t)b*CINC*NPIX + n;
  float* ob = out + (size_t)b*CINC*NPIX + n;
  #pragma unroll
  for (int gg = 0; gg < NG; ++gg) {
    float rn = 1.f / (TEPS + ab[gg*CHP + 64]);
    #pragma unroll 4
    for (int cc = 0; cc < 64; ++cc) {
      int ch = gg*64 + cc;
      float res = ab[gg*CHP + cc] * rn;
      float fv  = fb[(size_t)ch*NPIX];
      ob[(size_t)ch*NPIX] = gam*res + fv;
    }
  }
}

// ---------------------------------------------------------------------------
extern "C" void kernel_launch(void* const* d_in, const int* in_sizes, int n_in,
                              void* d_out, int out_size, void* d_ws, size_t ws_size,
                              hipStream_t stream)
{
  const float* f     = (const float*)d_in[0];
  const float* g     = (const float*)d_in[1];
  const float* We    = (const float*)d_in[2];
  const float* Wc    = (const float*)d_in[3];
  const float* Wg    = (const float*)d_in[4];
  const float* beta  = (const float*)d_in[5];
  const float* gamma = (const float*)d_in[6];
  const int* order   = (const int*)d_in[7];
  const int* parent  = (const int*)d_in[8];
  float* out = (float*)d_out;

  char* ws = (char*)d_ws;
  size_t off = 0;
  auto carve = [&](size_t bytes) -> void* {
    void* p = ws + off;
    off = (off + bytes + 255) & ~(size_t)255;
    return p;
  };
  float* emb = (float*)carve((size_t)NB*NPIX*NROWS*4);   // 13.5 MB
  float* w   = (float*)carve((size_t)NB*NPIX*NG*4);      // 0.4 MB
  float* xsp = (float*)carve((size_t)NB*NPIX*260*4);     // 26.6 MB
  float* agg = (float*)carve((size_t)NB*NPIX*NODEF*4);   // 32.8 MB
  int* cs  = (int*)carve((size_t)NB*NPIX*4);
  int* ce  = (int*)carve((size_t)NB*NPIX*4);
  int* ls  = (int*)carve((size_t)NB*(NPIX+2)*4);
  int* nl  = (int*)carve((size_t)NB*4);
  int* inv = (int*)carve((size_t)NB*NPIX*4);

  hipLaunchKernelGGL(prep_kernel,    dim3(NB),           dim3(256), 0, stream,
                     order, parent, cs, ce, ls, nl, inv);
  hipLaunchKernelGGL(gemm_kernel,    dim3(NPIX/TP, NB),  dim3(512), 0, stream,
                     f, g, We, Wc, Wg, emb);
  hipLaunchKernelGGL(wdist_kernel,   dim3(NB*NPIX/256),  dim3(256), 0, stream,
                     emb, order, parent, beta, w);
  hipLaunchKernelGGL(xbuild_kernel,  dim3(NB*NPIX/256),  dim3(256), 0, stream,
                     f, emb, xsp);
  hipLaunchKernelGGL(gather_kernel,  dim3(NB*100),       dim3(256), 0, stream,
                     xsp, order, agg);
  hipLaunchKernelGGL(sweep_kernel,   dim3(NB*NG),        dim3(256), 0, stream,
                     agg, w, parent, cs, ce, ls, nl);
  hipLaunchKernelGGL(epilogue_kernel,dim3(NB*NPIX/256),  dim3(256), 0, stream,
                     agg, inv, f, gamma, out);
}

// Round 4
// 524.397 us; speedup vs baseline: 3.8461x; 3.8461x over previous
//
#include <hip/hip_runtime.h>
#include <math.h>

// Problem constants (B, CIN, CGD, CE, G, H, W) = (4, 256, 256, 64, 4, 80, 80)
#define NB    4
#define CINC  256
#define NG    4
#define NPIX  6400          // H*W
#define NROWS 132           // 64 embed + 64 guide_embed + 4 conf
#define CHG   65            // tree-filter channels per group (64 + norm)
#define CHP   80            // padded per-group stride in node-major agg
#define NODEF (NG*CHP)      // 320 floats per node
#define TEPS  1e-8f
#define TP    128           // gemm position tile
#define KC    32            // gemm K chunk
#define SCH   5             // sweep channels per block (13 chunks * 5 = 65)
#define SPITCH 6401         // LDS pitch for s_agg (bank+1 per lane)

typedef unsigned short u16;
typedef unsigned int   u32;

// ---------------------------------------------------------------------------
// Preprocessing: per batch — levels via pointer doubling, level starts,
// u16 parent copy, inverse order.
// ---------------------------------------------------------------------------
__global__ __launch_bounds__(256) void prep_kernel(
    const int* __restrict__ order, const int* __restrict__ parent,
    u16* __restrict__ par16, int* __restrict__ ls,
    int* __restrict__ nl, int* __restrict__ inv)
{
  const int b = blockIdx.x;
  const int tid = threadIdx.x;
  const int* par = parent + b*NPIX;
  const int* ord = order + b*NPIX;
  __shared__ int lvl[NPIX];   // 25.6 KB
  __shared__ int anc[NPIX];   // 25.6 KB
  __shared__ int smax;

  #pragma unroll
  for (int it = 0; it < NPIX/256; ++it) {
    int k = tid + it*256;
    int p = par[k];
    lvl[k] = (k == 0) ? 0 : 1;
    anc[k] = p;
    inv[b*NPIX + ord[k]] = k;
    par16[b*NPIX + k] = (u16)p;
  }
  __syncthreads();

  // depth via pointer doubling: 13 rounds (2^13 = 8192 > 6400)
  for (int r = 0; r < 13; ++r) {
    int nlv[NPIX/256], nan_[NPIX/256];
    #pragma unroll
    for (int it = 0; it < NPIX/256; ++it) {
      int k = tid + it*256;
      int a = anc[k];
      nlv[it]  = lvl[k] + lvl[a];
      nan_[it] = anc[a];
    }
    __syncthreads();
    #pragma unroll
    for (int it = 0; it < NPIX/256; ++it) {
      int k = tid + it*256;
      lvl[k] = nlv[it];
      anc[k] = nan_[it];
    }
    __syncthreads();
  }

  if (tid == 0) smax = 0;
  __syncthreads();
  int m = 0;
  #pragma unroll
  for (int it = 0; it < NPIX/256; ++it) m = max(m, lvl[tid + it*256]);
  atomicMax(&smax, m);
  __syncthreads();
  if (tid == 0) {
    nl[b] = smax + 1;
    ls[b*(NPIX+2) + smax + 1] = NPIX;
  }
  #pragma unroll
  for (int it = 0; it < NPIX/256; ++it) {
    int k = tid + it*256;
    // levels are contiguous position ranges (BFS order)
    if (k == 0 || lvl[k] != lvl[k-1]) ls[b*(NPIX+2) + lvl[k]] = k;
  }
}

// ---------------------------------------------------------------------------
// GEMM: emb_all[b][n][r], r in [0,64)=W_embed@f, [64,128)=W_guide@g,
// [128,132)=sigmoid(W_conf@f). Node-major output for later gathers.
// ---------------------------------------------------------------------------
__global__ __launch_bounds__(512) void gemm_kernel(
    const float* __restrict__ f, const float* __restrict__ g,
    const float* __restrict__ We, const float* __restrict__ Wc,
    const float* __restrict__ Wg, float* __restrict__ emb)
{
  const int b  = blockIdx.y;
  const int t0 = blockIdx.x * TP;
  const int tid = threadIdx.x;
  const int i = tid >> 5;   // 0..15 (row group)
  const int j = tid & 31;   // 0..31 (position)

  __shared__ float fT[KC][TP];     // 16 KB
  __shared__ float gT[KC][TP];     // 16 KB
  __shared__ float wT[NROWS][KC];  // 16.9 KB

  float acc[9][4];
  #pragma unroll
  for (int a = 0; a < 9; ++a)
    #pragma unroll
    for (int p = 0; p < 4; ++p) acc[a][p] = 0.f;

  const float* fb = f + (size_t)b*CINC*NPIX;
  const float* gb = g + (size_t)b*CINC*NPIX;

  for (int kc = 0; kc < CINC; kc += KC) {
    {
      int idx = tid * 8;
      int kk = idx / TP, p = idx - kk*TP;
      const float4* srcf = reinterpret_cast<const float4*>(fb + (size_t)(kc+kk)*NPIX + t0 + p);
      const float4* srcg = reinterpret_cast<const float4*>(gb + (size_t)(kc+kk)*NPIX + t0 + p);
      float4 v0 = srcf[0], v1 = srcf[1];
      fT[kk][p+0]=v0.x; fT[kk][p+1]=v0.y; fT[kk][p+2]=v0.z; fT[kk][p+3]=v0.w;
      fT[kk][p+4]=v1.x; fT[kk][p+5]=v1.y; fT[kk][p+6]=v1.z; fT[kk][p+7]=v1.w;
      v0 = srcg[0]; v1 = srcg[1];
      gT[kk][p+0]=v0.x; gT[kk][p+1]=v0.y; gT[kk][p+2]=v0.z; gT[kk][p+3]=v0.w;
      gT[kk][p+4]=v1.x; gT[kk][p+5]=v1.y; gT[kk][p+6]=v1.z; gT[kk][p+7]=v1.w;
    }
    for (int s = tid; s < 528; s += 512) {
      int idx = s * 8;
      int r = idx / KC, kb = idx - r*KC;
      const float* wsrc;
      if (r < 64)       wsrc = We + r*CINC + kc + kb;
      else if (r < 128) wsrc = Wg + (r-64)*CINC + kc + kb;
      else              wsrc = Wc + (r-128)*CINC + kc + kb;
      const float4* wv = reinterpret_cast<const float4*>(wsrc);
      float4 v0 = wv[0], v1 = wv[1];
      wT[r][kb+0]=v0.x; wT[r][kb+1]=v0.y; wT[r][kb+2]=v0.z; wT[r][kb+3]=v0.w;
      wT[r][kb+4]=v1.x; wT[r][kb+5]=v1.y; wT[r][kb+6]=v1.z; wT[r][kb+7]=v1.w;
    }
    __syncthreads();

    #pragma unroll 4
    for (int kk = 0; kk < KC; ++kk) {
      float xf0 = fT[kk][j], xf1 = fT[kk][j+32], xf2 = fT[kk][j+64], xf3 = fT[kk][j+96];
      float xg0 = gT[kk][j], xg1 = gT[kk][j+32], xg2 = gT[kk][j+64], xg3 = gT[kk][j+96];
      #pragma unroll
      for (int rr = 0; rr < 4; ++rr) {
        float a = wT[i + 16*rr][kk];
        acc[rr][0] += a*xf0; acc[rr][1] += a*xf1; acc[rr][2] += a*xf2; acc[rr][3] += a*xf3;
      }
      #pragma unroll
      for (int rr = 4; rr < 8; ++rr) {
        float a = wT[i + 16*rr][kk];
        acc[rr][0] += a*xg0; acc[rr][1] += a*xg1; acc[rr][2] += a*xg2; acc[rr][3] += a*xg3;
      }
      if (i < 4) {
        float a = wT[128 + i][kk];
        acc[8][0] += a*xf0; acc[8][1] += a*xf1; acc[8][2] += a*xf2; acc[8][3] += a*xf3;
      }
    }
    __syncthreads();
  }

  float* eb = emb + (size_t)b*NPIX*NROWS;
  #pragma unroll
  for (int rr = 0; rr < 8; ++rr) {
    int r = i + 16*rr;
    #pragma unroll
    for (int p = 0; p < 4; ++p) {
      int n = t0 + j + 32*p;
      eb[(size_t)n*NROWS + r] = acc[rr][p];
    }
  }
  if (i < 4) {
    int r = 128 + i;
    #pragma unroll
    for (int p = 0; p < 4; ++p) {
      int n = t0 + j + 32*p;
      eb[(size_t)n*NROWS + r] = 1.f / (1.f + expf(-acc[8][p]));
    }
  }
}

// ---------------------------------------------------------------------------
// Edge weights, quantized u16, transposed: wq[b][g][k] = round(65535*w)
// ---------------------------------------------------------------------------
__global__ __launch_bounds__(256) void wdist_kernel(
    const float* __restrict__ emb, const int* __restrict__ order,
    const int* __restrict__ parent, const float* __restrict__ beta,
    u16* __restrict__ wq)
{
  int idx = blockIdx.x*256 + threadIdx.x;   // b*NPIX + k
  int b = idx / NPIX;
  int k = idx - b*NPIX;
  int n  = order[idx];
  int kp = parent[idx];
  int np = order[b*NPIX + kp];
  const float4* e0 = reinterpret_cast<const float4*>(emb + ((size_t)b*NPIX + n )*NROWS);
  const float4* e1 = reinterpret_cast<const float4*>(emb + ((size_t)b*NPIX + np)*NROWS);
  float d[NG] = {0.f, 0.f, 0.f, 0.f};
  #pragma unroll
  for (int q = 0; q < 32; ++q) {            // channels 0..127 (embed then guide_embed)
    float4 a = e0[q], c = e1[q];
    int gg = (q & 15) >> 2;                 // group = (channel%64)/16
    float t0 = a.x-c.x, t1 = a.y-c.y, t2 = a.z-c.z, t3 = a.w-c.w;
    d[gg] += t0*t0 + t1*t1 + t2*t2 + t3*t3;
  }
  #pragma unroll
  for (int gg = 0; gg < NG; ++gg) {
    float bg = beta[gg];
    float w = expf(-(d[gg] + bg*bg));
    wq[((size_t)(b*NG+gg))*NPIX + k] = (u16)(w*65535.f + 0.5f);
  }
}

// ---------------------------------------------------------------------------
// x in spatial space: xsp[b][n][g*65+c] = f[g*64+c]*conf[g]; c=64 -> conf[g]
// ---------------------------------------------------------------------------
__global__ __launch_bounds__(256) void xbuild_kernel(
    const float* __restrict__ f, const float* __restrict__ emb,
    float* __restrict__ xsp)
{
  int idx = blockIdx.x*256 + threadIdx.x;   // b*NPIX + n
  int b = idx / NPIX, n = idx - b*NPIX;
  const float* eb = emb + (size_t)idx*NROWS;
  float cf[NG];
  #pragma unroll
  for (int gg = 0; gg < NG; ++gg) cf[gg] = eb[128 + gg];
  const float* fb = f + (size_t)b*CINC*NPIX + n;
  float* xb = xsp + (size_t)idx*260;
  #pragma unroll 4
  for (int ch = 0; ch < CINC; ++ch) {
    int gg = ch >> 6, cc = ch & 63;
    xb[gg*CHG + cc] = fb[(size_t)ch*NPIX] * cf[gg];
  }
  #pragma unroll
  for (int gg = 0; gg < NG; ++gg) xb[gg*CHG + 64] = cf[gg];
}

// ---------------------------------------------------------------------------
// Transpose-gather to channel-major ordered layout: aggT[b][g][c][k]
// Block = (b, g, 64-node tile). LDS-tiled so both sides are coalesced.
// ---------------------------------------------------------------------------
__global__ __launch_bounds__(256) void gatherT_kernel(
    const float* __restrict__ xsp, const int* __restrict__ order,
    float* __restrict__ aggT)
{
  int bid = blockIdx.x;                 // b*400 + g*100 + tile
  int b = bid / 400, r = bid - b*400;
  int g = r / 100, k0 = (r - g*100) * 64;
  const int tid = threadIdx.x;

  __shared__ float tile[64][66];
  __shared__ int s_ord[64];
  if (tid < 64) s_ord[tid] = order[b*NPIX + k0 + tid];
  __syncthreads();

  for (int idx = tid; idx < 64*65; idx += 256) {
    int kk = idx / 65, c = idx - kk*65;
    tile[kk][c] = xsp[((size_t)b*NPIX + s_ord[kk])*260 + g*65 + c];
  }
  __syncthreads();
  float* dst = aggT + ((size_t)(b*NG+g)*CHG)*NPIX;
  for (int idx = tid; idx < 65*64; idx += 256) {
    int c = idx / 64, kk = idx - c*64;
    dst[(size_t)c*NPIX + k0 + kk] = tile[kk][c];
  }
}

// ---------------------------------------------------------------------------
// Tree filter, LDS-resident. Block = (b, g, 5-channel chunk), 64 threads
// (single wave -> barrier is just a waitcnt). s_agg stride 6401 => lane
// stride 1 bank. w u16 fixed-point, parent u16. Level bounds prefetched.
// ---------------------------------------------------------------------------
__global__ __launch_bounds__(64, 1) void sweep_kernel(
    const float* __restrict__ aggT, const u16* __restrict__ wq,
    const u16* __restrict__ par16, const int* __restrict__ ls,
    const int* __restrict__ nl, float* __restrict__ agg)
{
  extern __shared__ char smem[];
  float* s_agg = (float*)smem;                         // 5*6401 floats = 128020 B
  u32*  s_w32  = (u32*)(smem + 128032);                // 12800 B (6400 u16)
  u32*  s_p32  = (u32*)(smem + 128032 + 12800);        // 12800 B
  u16*  s_w    = (u16*)s_w32;
  u16*  s_par  = (u16*)s_p32;

  const int bid = blockIdx.x;
  const int b = bid / (NG*13);
  const int r = bid - b*(NG*13);
  const int g = r / 13;
  const int ch0 = (r - g*13) * SCH;
  const int tid = threadIdx.x;
  const int bg = b*NG + g;

  // ---- load state: aggT (coalesced float4), w, parent ----
  #pragma unroll
  for (int c = 0; c < SCH; ++c) {
    const float4* src = reinterpret_cast<const float4*>(aggT + ((size_t)bg*CHG + ch0 + c)*NPIX);
    float* dst = s_agg + c*SPITCH;
    for (int i = tid; i < NPIX/4; i += 64) {
      float4 v = src[i];
      int k = i*4;
      dst[k] = v.x; dst[k+1] = v.y; dst[k+2] = v.z; dst[k+3] = v.w;
    }
  }
  {
    const u32* wsrc = reinterpret_cast<const u32*>(wq + (size_t)bg*NPIX);
    const u32* psrc = reinterpret_cast<const u32*>(par16 + (size_t)b*NPIX);
    for (int i = tid; i < NPIX/2; i += 64) {
      s_w32[i] = wsrc[i];
      s_p32[i] = psrc[i];
    }
  }
  const int* lsb = ls + b*(NPIX+2);
  const int L = nl[b];
  __syncthreads();

  const float qs = 1.0f/65535.0f;

  // ---- UP: children (level lev+1) scatter-add into parents ----
  {
    int lev = L-2;
    int A = lsb[lev], Bv = lsb[lev+1], Cv = lsb[lev+2];
    while (lev >= 0) {
      int nxt = (lev > 0) ? lsb[lev-1] : 0;   // prefetch next level start
      int cstart = Bv;
      int items = (Cv - Bv) * SCH;
      for (int t = tid; t < items; t += 64) {
        int node = t / SCH, c = t - node*SCH;
        int k = cstart + node;
        int p = s_par[k];
        float wv = (float)s_w[k] * qs;
        float v = s_agg[c*SPITCH + k];
        atomicAdd(&s_agg[c*SPITCH + p], wv*v);
      }
      __syncthreads();
      Cv = Bv; Bv = A; A = nxt; --lev;
    }
  }

  // ---- DOWN (in place): out[k] = a + w*(out[p] - w*a) ----
  {
    int lev = 1;
    int A = lsb[1], Bv = lsb[2];
    while (lev < L) {
      int nxt = lsb[lev+2];                   // prefetch (garbage at end, unused)
      int s = A;
      int items = (Bv - A) * SCH;
      for (int t = tid; t < items; t += 64) {
        int node = t / SCH, c = t - node*SCH;
        int k = s + node;
        int p = s_par[k];
        float wv = (float)s_w[k] * qs;
        float a  = s_agg[c*SPITCH + k];
        float op = s_agg[c*SPITCH + p];
        s_agg[c*SPITCH + k] = fmaf(wv, op - wv*a, a);
      }
      __syncthreads();
      A = Bv; Bv = nxt; ++lev;
    }
  }

  // ---- writeback node-major for epilogue ----
  for (int t = tid; t < NPIX*SCH; t += 64) {
    int k = t / SCH, c = t - k*SCH;
    agg[((size_t)b*NPIX + k)*NODEF + g*CHP + ch0 + c] = s_agg[c*SPITCH + k];
  }
}

// ---------------------------------------------------------------------------
// Epilogue: gather back to spatial, normalize, residual, store
// ---------------------------------------------------------------------------
__global__ __launch_bounds__(256) void epilogue_kernel(
    const float* __restrict__ agg, const int* __restrict__ inv,
    const float* __restrict__ f, const float* __restrict__ gamma,
    float* __restrict__ out)
{
  int idx = blockIdx.x*256 + threadIdx.x;   // b*NPIX + n
  int b = idx / NPIX, n = idx - b*NPIX;
  int k = inv[idx];
  const float* ab = agg + ((size_t)b*NPIX + k)*NODEF;
  float gam = gamma[0];
  const float* fb = f + (size_t)b*CINC*NPIX + n;
  float* ob = out + (size_t)b*CINC*NPIX + n;
  #pragma unroll
  for (int gg = 0; gg < NG; ++gg) {
    float rn = 1.f / (TEPS + ab[gg*CHP + 64]);
    #pragma unroll 4
    for (int cc = 0; cc < 64; ++cc) {
      int ch = gg*64 + cc;
      float res = ab[gg*CHP + cc] * rn;
      float fv  = fb[(size_t)ch*NPIX];
      ob[(size_t)ch*NPIX] = gam*res + fv;
    }
  }
}

// ---------------------------------------------------------------------------
extern "C" void kernel_launch(void* const* d_in, const int* in_sizes, int n_in,
                              void* d_out, int out_size, void* d_ws, size_t ws_size,
                              hipStream_t stream)
{
  const float* f     = (const float*)d_in[0];
  const float* g     = (const float*)d_in[1];
  const float* We    = (const float*)d_in[2];
  const float* Wc    = (const float*)d_in[3];
  const float* Wg    = (const float*)d_in[4];
  const float* beta  = (const float*)d_in[5];
  const float* gamma = (const float*)d_in[6];
  const int* order   = (const int*)d_in[7];
  const int* parent  = (const int*)d_in[8];
  float* out = (float*)d_out;

  char* ws = (char*)d_ws;
  size_t off = 0;
  auto carve = [&](size_t bytes) -> void* {
    void* p = ws + off;
    off = (off + bytes + 255) & ~(size_t)255;
    return p;
  };
  // agg (node-major, 32.8 MB) aliases [emb + xsp] (40.2 MB), both dead
  // by the time sweep_kernel writes it.
  float* agg = (float*)ws;
  float* emb = (float*)carve((size_t)NB*NPIX*NROWS*4);     // 13.5 MB
  float* xsp = (float*)carve((size_t)NB*NPIX*260*4);       // 26.6 MB
  float* aggT= (float*)carve((size_t)NB*NG*CHG*NPIX*4);    // 26.6 MB
  u16*  wq   = (u16*) carve((size_t)NB*NG*NPIX*2);         // 0.2 MB
  u16*  par16= (u16*) carve((size_t)NB*NPIX*2);
  int*  ls   = (int*) carve((size_t)NB*(NPIX+2)*4);
  int*  nl   = (int*) carve((size_t)NB*4);
  int*  inv  = (int*) carve((size_t)NB*NPIX*4);

  const int sweep_lds = 128032 + 12800 + 12800;            // 153632 B
  hipFuncSetAttribute((const void*)sweep_kernel,
                      hipFuncAttributeMaxDynamicSharedMemorySize, sweep_lds);

  hipLaunchKernelGGL(prep_kernel,    dim3(NB),           dim3(256), 0, stream,
                     order, parent, par16, ls, nl, inv);
  hipLaunchKernelGGL(gemm_kernel,    dim3(NPIX/TP, NB),  dim3(512), 0, stream,
                     f, g, We, Wc, Wg, emb);
  hipLaunchKernelGGL(wdist_kernel,   dim3(NB*NPIX/256),  dim3(256), 0, stream,
                     emb, order, parent, beta, wq);
  hipLaunchKernelGGL(xbuild_kernel,  dim3(NB*NPIX/256),  dim3(256), 0, stream,
                     f, emb, xsp);
  hipLaunchKernelGGL(gatherT_kernel, dim3(NB*NG*100),    dim3(256), 0, stream,
                     xsp, order, aggT);
  hipLaunchKernelGGL(sweep_kernel,   dim3(NB*NG*13),     dim3(64), sweep_lds, stream,
                     aggT, wq, par16, ls, nl, agg);
  hipLaunchKernelGGL(epilogue_kernel,dim3(NB*NPIX/256),  dim3(256), 0, stream,
                     agg, inv, f, gamma, out);
}